// Round 3
// baseline (88.462 us; speedup 1.0000x reference)
//
#include <hip/hip_runtime.h>

#define S_TOK 8192
#define NB 8
#define HQ 32
#define HKV 8
#define DH 128
#define KK 128
#define DIM 4096

// ---------------- GEMV core: 8 rows/block, 256 threads, x LDS-staged ----------------
// Thread t owns rows r0 = rstart + (t>>6) and r1 = r0 + 4; lane = t&63.
// x [NB][DIM] is staged through xs (32 KB) in 4 chunks of 1024 floats per batch,
// so x global traffic is 128 KB per block instead of 1 MB.
__device__ __forceinline__ void gemv8(const float* __restrict__ W,
                                      const float* __restrict__ x,
                                      float* __restrict__ y,
                                      int rstart, int t, float4* xs) {
    const int rp = t >> 6;          // wave id 0..3
    const int lane = t & 63;
    const int r0 = rstart + rp, r1 = rstart + rp + 4;
    const float4* W4 = (const float4*)W;
    const float4* x4 = (const float4*)x;
    float acc0[NB], acc1[NB];
#pragma unroll
    for (int b = 0; b < NB; ++b) { acc0[b] = 0.f; acc1[b] = 0.f; }

    for (int ck = 0; ck < 4; ++ck) {
        __syncthreads();            // xs safe to overwrite
#pragma unroll
        for (int i = 0; i < 8; ++i) {
            int f = t + i * 256;    // 0..2047
            int b = f >> 8, c = f & 255;
            xs[b * 256 + c] = x4[(size_t)b * (DIM / 4) + ck * 256 + c];
        }
        __syncthreads();
#pragma unroll
        for (int cc = 0; cc < 4; ++cc) {
            const int c = lane + cc * 64;
            float4 w0 = W4[(size_t)r0 * (DIM / 4) + ck * 256 + c];
            float4 w1 = W4[(size_t)r1 * (DIM / 4) + ck * 256 + c];
#pragma unroll
            for (int b = 0; b < NB; ++b) {
                float4 xv = xs[b * 256 + c];
                acc0[b] += w0.x * xv.x + w0.y * xv.y + w0.z * xv.z + w0.w * xv.w;
                acc1[b] += w1.x * xv.x + w1.y * xv.y + w1.z * xv.z + w1.w * xv.w;
            }
        }
    }
#pragma unroll
    for (int b = 0; b < NB; ++b) {
#pragma unroll
        for (int o = 32; o > 0; o >>= 1) {
            acc0[b] += __shfl_down(acc0[b], o);
            acc1[b] += __shfl_down(acc1[b], o);
        }
    }
    if (lane == 0) {
#pragma unroll
        for (int b = 0; b < NB; ++b) {
            y[(size_t)b * DIM + r0] = acc0[b];
            y[(size_t)b * DIM + r1] = acc1[b];
        }
    }
}

// ---------------- Kernel 1: fused { imp+topk (blocks 0..7) | Wq GEMV (blocks 8..519) } ----
// top-k order: value descending, index ascending on ties (lax.top_k semantics).
// Importance is computed in-block with the SAME serial h=0..31 summation order as the
// verified round-1 kernel -> bit-identical selection.
__global__ __launch_bounds__(256) void topk_gemvq_kernel(const float* __restrict__ attn_w,
                                                         const float* __restrict__ Wq,
                                                         const float* __restrict__ hidden,
                                                         int* __restrict__ topk,
                                                         float* __restrict__ q) {
    __shared__ __align__(16) float4 xs[NB * 256];   // 32 KB (gemv path)
    __shared__ __align__(16) unsigned mb[S_TOK];    // 32 KB (topk path)
    __shared__ __align__(16) int hist[256];
    __shared__ unsigned sprefix;
    __shared__ int skrem;
    __shared__ int nsel;
    __shared__ unsigned selb[KK];
    __shared__ int seli[KK];

    const int t = threadIdx.x;
    const int bl = blockIdx.x;

    if (bl >= NB) {
        gemv8(Wq, hidden, q, (bl - NB) * 8, t, xs);
        return;
    }

    // ---------- importance (serial 32-head sum, bit-exact vs round 1) ----------
    const int b = bl;
    for (int base = t * 4; base < S_TOK; base += 1024) {
        float4 acc = {0.f, 0.f, 0.f, 0.f};
#pragma unroll 8
        for (int h = 0; h < HQ; ++h) {
            float4 w = *(const float4*)(attn_w + (size_t)(b * HQ + h) * S_TOK + base);
            acc.x += w.x; acc.y += w.y; acc.z += w.z; acc.w += w.w;
        }
        float vals[4] = {acc.x, acc.y, acc.z, acc.w};
#pragma unroll
        for (int j = 0; j < 4; ++j) {
            unsigned u = __float_as_uint(vals[j] * (1.0f / 32.0f));
            u = (u & 0x80000000u) ? ~u : (u | 0x80000000u);   // monotone map
            mb[base + j] = u;
        }
    }
    if (t == 0) { sprefix = 0u; skrem = KK; nsel = 0; }
    __syncthreads();

    // ---------- radix-256 select: bit pattern T of the 128th largest ----------
    for (int shift = 24; shift >= 0; shift -= 8) {
        hist[t] = 0;
        __syncthreads();
        const unsigned pfx = sprefix;
        const int krem = skrem;
        if (shift == 24) {
            // values cluster into few exponent bins -> ballot-aggregate
            for (int i = t; i < S_TOK; i += 256) {
                int bin = mb[i] >> 24;
                unsigned long long rem = __ballot(1);
                while (rem) {
                    int fl = (int)__builtin_ctzll(rem);
                    int fbin = __shfl(bin, fl);
                    unsigned long long match = __ballot(bin == fbin);
                    if ((t & 63) == fl) atomicAdd(&hist[fbin], (int)__popcll(match));
                    rem &= ~match;
                }
            }
        } else {
            const unsigned pmask = 0xFFFFFFFFu << (shift + 8);
            for (int i = t; i < S_TOK; i += 256) {
                unsigned u = mb[i];
                if ((u & pmask) == pfx) atomicAdd(&hist[(u >> shift) & 255], 1);
            }
        }
        __syncthreads();
        // wave 0: parallel descending-bin scan
        if (t < 64) {
            int4 h4 = *(const int4*)&hist[252 - 4 * t];
            int h0 = h4.w, h1 = h4.z, h2 = h4.y, h3 = h4.x;   // descending-bin order
            int c0 = h0, c1 = c0 + h1, c2 = c1 + h2, c3 = c2 + h3;
            int inc = c3;
#pragma unroll
            for (int o = 1; o < 64; o <<= 1) {
                int yv = __shfl_up(inc, o);
                if (t >= o) inc += yv;
            }
            int excl = inc - c3;
            int cand = -1, before = 0;
            if      (excl + c0 >= krem) { cand = 0; before = excl; }
            else if (excl + c1 >= krem) { cand = 1; before = excl + c0; }
            else if (excl + c2 >= krem) { cand = 2; before = excl + c1; }
            else if (excl + c3 >= krem) { cand = 3; before = excl + c2; }
            unsigned long long ball = __ballot(cand >= 0);
            int win = (int)__builtin_ctzll(ball);
            if (t == win) {
                int p = 4 * t + cand;
                sprefix = pfx | ((unsigned)(255 - p) << shift);
                skrem = krem - before;
            }
        }
        __syncthreads();
    }
    const unsigned T = sprefix;

    // collect strictly-greater (unordered; sorted below)
    for (int i = t; i < S_TOK; i += 256) {
        unsigned u = mb[i];
        if (u > T) {
            int p = atomicAdd(&nsel, 1);
            selb[p] = u; seli[p] = i;
        }
    }
    __syncthreads();
    const int g = nsel;
    const int r = KK - g;          // >= 1 by construction

    // wave 0: ordered scan collects the r smallest-index ties
    if (t < 64) {
        int found = 0;
        for (int base0 = 0; base0 < S_TOK && found < r; base0 += 64) {
            bool is_tie = (mb[base0 + t] == T);
            unsigned long long ball = __ballot(is_tie);
            int pos = (int)__popcll(ball & ((1ull << t) - 1ull));
            if (is_tie && found + pos < r) {
                selb[g + found + pos] = T;
                seli[g + found + pos] = base0 + t;
            }
            found += (int)__popcll(ball);
        }
    }
    __syncthreads();

    // bitonic sort 128: value descending, index ascending
    for (int ksz = 2; ksz <= KK; ksz <<= 1) {
        for (int j = ksz >> 1; j > 0; j >>= 1) {
            if (t < KK) {
                int i = t, l = i ^ j;
                if (l > i) {
                    bool up = ((i & ksz) == 0);
                    unsigned ab = selb[i], cb = selb[l];
                    int ai = seli[i], ci = seli[l];
                    bool aFirst = (ab > cb) || (ab == cb && ai < ci);
                    if (up ? !aFirst : aFirst) {
                        selb[i] = cb; selb[l] = ab;
                        seli[i] = ci; seli[l] = ai;
                    }
                }
            }
            __syncthreads();
        }
    }
    if (t < KK) topk[b * KK + t] = seli[t];
}

// ---------------- Kernel 2: pruned attention, 512 threads per (b,h) ----------------
__global__ __launch_bounds__(512) void attn_kernel(const float* __restrict__ q,
                                                   const float* __restrict__ k,
                                                   const float* __restrict__ v,
                                                   const int* __restrict__ topk,
                                                   float* __restrict__ ctx,
                                                   float* __restrict__ probs_out) {
    const int bh = blockIdx.x;
    const int b = bh >> 5, h = bh & 31, kvh = h >> 2;
    const int t = threadIdx.x;   // 512 threads

    __shared__ float qs[DH];
    __shared__ float scs[KK];
    __shared__ float ps[KK];
    __shared__ int idxs[KK];
    __shared__ float red2[2];
    __shared__ float red3[2];
    __shared__ float part[3][DH];

    if (t < DH) qs[t] = q[(size_t)(b * HQ + h) * DH + t] * 0.088388347648318447f; // 1/sqrt(128)
    if (t < KK) idxs[t] = topk[b * KK + t];
    __syncthreads();

    // scores: 4 threads per token, 32-dim quarter dots
    {
        const int tok = t >> 2, qpart = t & 3;
        const float4* k4 = (const float4*)(k +
            ((size_t)(b * HKV + kvh) * S_TOK + idxs[tok]) * DH + qpart * 32);
        float sc = 0.f;
#pragma unroll
        for (int d4 = 0; d4 < 8; ++d4) {
            float4 kv = k4[d4];
            int d0 = qpart * 32 + d4 * 4;
            sc += qs[d0] * kv.x + qs[d0 + 1] * kv.y + qs[d0 + 2] * kv.z + qs[d0 + 3] * kv.w;
        }
        sc += __shfl_xor(sc, 1);
        sc += __shfl_xor(sc, 2);
        if (qpart == 0) scs[tok] = sc;
    }
    __syncthreads();

    // softmax over 128 tokens (threads 0..127 hold one token each)
    float sc = (t < KK) ? scs[t] : -3.4e38f;
    if (t < KK) {
        float m = sc;
        for (int o = 32; o > 0; o >>= 1) m = fmaxf(m, __shfl_down(m, o));
        if ((t & 63) == 0) red2[t >> 6] = m;
    }
    __syncthreads();
    const float mx = fmaxf(red2[0], red2[1]);
    float p = 0.f;
    if (t < KK) {
        p = expf(sc - mx);
        float sm = p;
        for (int o = 32; o > 0; o >>= 1) sm += __shfl_down(sm, o);
        if ((t & 63) == 0) red3[t >> 6] = sm;
    }
    __syncthreads();
    if (t < KK) {
        p /= (red3[0] + red3[1]);
        ps[t] = p;
        probs_out[(size_t)(b * HQ + h) * KK + t] = p;
    }
    __syncthreads();

    // PV: 4 groups x 128 dims, 32 tokens per group, LDS combine
    {
        const int d = t & (DH - 1), grp = t >> 7;
        const float* vbase = v + (size_t)(b * HKV + kvh) * S_TOK * DH;
        float acc = 0.f;
        const int s0 = grp * 32;
#pragma unroll 4
        for (int s2 = s0; s2 < s0 + 32; ++s2) {
            acc += ps[s2] * vbase[(size_t)idxs[s2] * DH + d];
        }
        if (grp) part[grp - 1][d] = acc;
        __syncthreads();
        if (grp == 0)
            ctx[(size_t)(b * HQ + h) * DH + d] = acc + part[0][d] + part[1][d] + part[2][d];
    }
}

// ---------------- Kernel 3: Wo GEMV, 8 rows/block ----------------
__global__ __launch_bounds__(256) void gemv_wo_kernel(const float* __restrict__ Wo,
                                                      const float* __restrict__ ctx,
                                                      float* __restrict__ out) {
    __shared__ __align__(16) float4 xs[NB * 256];   // 32 KB
    gemv8(Wo, ctx, out, blockIdx.x * 8, threadIdx.x, xs);
}

// ---------------- launcher ----------------
extern "C" void kernel_launch(void* const* d_in, const int* in_sizes, int n_in,
                              void* d_out, int out_size, void* d_ws, size_t ws_size,
                              hipStream_t stream) {
    const float* hidden = (const float*)d_in[0];   // [8,1,4096]
    const float* attn_w = (const float*)d_in[1];   // [8,32,1,8192]
    const float* k      = (const float*)d_in[2];   // [8,8,8192,128]
    const float* v      = (const float*)d_in[3];   // [8,8,8192,128]
    const float* Wq     = (const float*)d_in[4];   // [4096,4096]
    const float* Wo     = (const float*)d_in[5];   // [4096,4096]

    float* out   = (float*)d_out;                  // [8,4096]
    float* probs = out + NB * DIM;                 // [8,32,1,128]

    char* ws = (char*)d_ws;
    int*   topkb = (int*)ws;                        // 8*128*4  =   4096 B
    float* q     = (float*)(ws + 4096);             // 8*4096*4 = 131072 B
    float* ctx   = (float*)(ws + 4096 + 131072);    // 8*4096*4 = 131072 B

    // blocks 0..7: importance+topk (reads attn_w directly); blocks 8..519: Wq GEMV.
    topk_gemvq_kernel<<<NB + 512, 256, 0, stream>>>(attn_w, Wq, hidden, topkb, q);
    attn_kernel<<<NB * HQ, 512, 0, stream>>>(q, k, v, topkb, ctx, probs);
    gemv_wo_kernel<<<512, 256, 0, stream>>>(Wo, ctx, out);
}